// Round 8
// baseline (537.454 us; speedup 1.0000x reference)
//
#include <hip/hip_runtime.h>

typedef __attribute__((ext_vector_type(4)))  float floatx4;
typedef __attribute__((ext_vector_type(16))) float floatx16;
typedef __attribute__((ext_vector_type(8)))  int   intx8;

// ---------------------------------------------------------------------------
// pack 4 floats (already clipped to +-448) into 4 e4m3 bytes, RNE
// ---------------------------------------------------------------------------
__device__ __forceinline__ unsigned int pack4_fp8(float f0, float f1, float f2, float f3) {
    int v = __builtin_amdgcn_cvt_pk_fp8_f32(f0, f1, 0, false);   // bytes 0,1
    v = __builtin_amdgcn_cvt_pk_fp8_f32(f2, f3, v, true);        // bytes 2,3
    return (unsigned int)v;
}

// async global->LDS, 16 B per lane. LDS dest is wave-uniform; HW writes
// dest + lane*16. Global src is per-lane (pre-swizzled to match).
__device__ __forceinline__ void gload16(const unsigned char* g, unsigned char* l) {
    __builtin_amdgcn_global_load_lds(
        (const __attribute__((address_space(1))) unsigned int*)g,
        (__attribute__((address_space(3))) unsigned int*)l, 16, 0, 0);
}

// ---------------------------------------------------------------------------
// Kernel 0: classify the weight buffer's on-device dtype.
// flag: 0 = raw fp8 bytes, 1 = bf16-upcast, 2 = f32-upcast.
// ---------------------------------------------------------------------------
__global__ void detect_kernel(const unsigned int* __restrict__ W, int* __restrict__ flag) {
    __shared__ int ok[2];  // [f32ok, bf16ok]
    if (threadIdx.x == 0) { ok[0] = 1; ok[1] = 1; }
    __syncthreads();
    int f32ok = 1, bf16ok = 1;
#pragma unroll
    for (int i = 0; i < 16; ++i) {
        unsigned int w = W[threadIdx.x * 16 + i];   // first 16 KB of buffer
        if (w & 0x000FFFFFu) f32ok = 0;
        if (w & 0x000F000Fu) bf16ok = 0;
    }
    if (!f32ok)  atomicAnd(&ok[0], 0);
    if (!bf16ok) atomicAnd(&ok[1], 0);
    __syncthreads();
    if (threadIdx.x == 0) *flag = ok[0] ? 2 : (ok[1] ? 1 : 0);
}

// ---------------------------------------------------------------------------
// Kernel 1: quantize x (fp32) -> q (fp8 e4m3fn), q = clip(x/s, +-448)
// ---------------------------------------------------------------------------
__global__ void quant_kernel(const float* __restrict__ x,
                             unsigned int* __restrict__ q,
                             const float* __restrict__ iscale, int n8) {
    int i = blockIdx.x * blockDim.x + threadIdx.x;
    if (i >= n8) return;
    float s = iscale[0];
    const float4* xv = (const float4*)x;
    float4 a = xv[2 * i];
    float4 b = xv[2 * i + 1];
    float v[8] = {a.x, a.y, a.z, a.w, b.x, b.y, b.z, b.w};
#pragma unroll
    for (int j = 0; j < 8; ++j) {
        float t = v[j] / s;
        v[j] = fminf(fmaxf(t, -448.0f), 448.0f);
    }
    q[2 * i]     = pack4_fp8(v[0], v[1], v[2], v[3]);
    q[2 * i + 1] = pack4_fp8(v[4], v[5], v[6], v[7]);
}

// ---------------------------------------------------------------------------
// Kernel 2: ingest weight [K,N] (any of the 3 dtypes) -> Wt [N,K] fp8 bytes,
// via 64x64 LDS tile. Single launch; runtime uniform branch on *flag.
// ---------------------------------------------------------------------------
template <int MODE>
__device__ __forceinline__ void ingest_body(const unsigned char* __restrict__ W,
                                            unsigned char* __restrict__ Wt,
                                            int K, int N,
                                            unsigned char (*tile)[68]) {
    const int k0 = blockIdx.y * 64;
    const int n0 = blockIdx.x * 64;
    const int t = threadIdx.x;          // 256 threads
    const int kr = t >> 2;              // k-row within tile
    const int cg = (t & 3) * 16;        // n-column group (16 values)
    const size_t eidx = (size_t)(k0 + kr) * N + (n0 + cg);  // element index

    unsigned int w4[4];
    if constexpr (MODE == 0) {          // raw fp8 bytes
        uint4 v = *(const uint4*)(W + eidx);
        w4[0] = v.x; w4[1] = v.y; w4[2] = v.z; w4[3] = v.w;
    } else if constexpr (MODE == 1) {   // bf16-upcast (2 B/elem)
        const uint4* p = (const uint4*)((const unsigned short*)W + eidx);
        uint4 A0 = p[0], A1 = p[1];
        unsigned int uw[8] = {A0.x, A0.y, A0.z, A0.w, A1.x, A1.y, A1.z, A1.w};
#pragma unroll
        for (int g = 0; g < 4; ++g) {
            float f0 = __uint_as_float((uw[2 * g] & 0xFFFFu) << 16);
            float f1 = __uint_as_float((uw[2 * g] >> 16) << 16);
            float f2 = __uint_as_float((uw[2 * g + 1] & 0xFFFFu) << 16);
            float f3 = __uint_as_float((uw[2 * g + 1] >> 16) << 16);
            w4[g] = pack4_fp8(f0, f1, f2, f3);
        }
    } else {                            // f32-upcast (4 B/elem)
        const float4* p = (const float4*)((const float*)W + eidx);
#pragma unroll
        for (int g = 0; g < 4; ++g) {
            float4 f = p[g];
            w4[g] = pack4_fp8(f.x, f.y, f.z, f.w);
        }
    }
#pragma unroll
    for (int g = 0; g < 4; ++g)
        *(unsigned int*)&tile[kr][cg + 4 * g] = w4[g];   // 4B-aligned (68%4==0)
    __syncthreads();

    const int nr = t >> 2;
    const int kg = (t & 3) * 16;
    uint4 o;
    unsigned int w[4];
#pragma unroll
    for (int g = 0; g < 4; ++g) {
        unsigned int b0 = tile[kg + g * 4 + 0][nr];
        unsigned int b1 = tile[kg + g * 4 + 1][nr];
        unsigned int b2 = tile[kg + g * 4 + 2][nr];
        unsigned int b3 = tile[kg + g * 4 + 3][nr];
        w[g] = b0 | (b1 << 8) | (b2 << 16) | (b3 << 24);
    }
    o.x = w[0]; o.y = w[1]; o.z = w[2]; o.w = w[3];
    *(uint4*)(Wt + (size_t)(n0 + nr) * K + k0 + kg) = o;  // 16B-aligned
}

__global__ void ingest_kernel(const unsigned char* __restrict__ W,
                              unsigned char* __restrict__ Wt,
                              const int* __restrict__ flag, int K, int N) {
    __shared__ __align__(16) unsigned char tile[64][68];
    const int mode = *flag;             // global & uniform -> no divergence
    if (mode == 0)      ingest_body<0>(W, Wt, K, N, tile);
    else if (mode == 1) ingest_body<1>(W, Wt, K, N, tile);
    else                ingest_body<2>(W, Wt, K, N, tile);
}

// ---------------------------------------------------------------------------
// Kernel 3: MX-scaled fp8 GEMM (scales = 1.0), 256x256 tile, BK=128,
// 8 waves (2M x 4N), 32x32x64 MFMA (r7, +19%), FREE-RUNNING tile body.
//
// ROUND-8 CHANGE (convoy fix / T3-minimum recipe): r5-r7 pinned MfmaUtil at
// 24-30% because the barrier-pair-per-phase structure serializes LDS-port
// time and MFMA time at BLOCK level (port-storm -> barrier -> MFMA-storm ->
// barrier, 4x/tile: (700+550+skew)*4 ~ 7000cy vs 2200cy MFMA floor).
// New: ZERO mid-tile barriers, ZERO explicit lgkm drains. Both A and B are
// staged 1-ahead at TILE TOP into the opposite dbuf half (last read at tile
// t-1; every wave's reads drained before its boundary-barrier arrival ->
// WAR-safe behind ONE barrier). Reads issued pipelined (16 up front, 4+4
// between MFMA quads); the COMPILER inserts counted lgkmcnt before each
// dependent MFMA (its verified strength, m97 asm). Waves de-sync and each
// wave's port traffic overlaps its own + other waves' MFMA.
// Boundary vmcnt(0) is free-by-construction: DMA issued at tile top, drain
// at tile end (~3000cy >> 900cy HBM latency). 2 sync ops/tile (was 9).
//
// LDS layout, fragment addressing, epilogue: unchanged from r7 (verified:
// 0 bank conflicts, correctness passed, WRITE amplification fixed).
// ---------------------------------------------------------------------------
__global__ __launch_bounds__(512, 2) void gemm_mxfp8_kernel(
    const unsigned char* __restrict__ A,   // [M,K] fp8
    const unsigned char* __restrict__ Bt,  // [N,K] fp8
    float* __restrict__ C,                 // [M,N] fp32
    const float* __restrict__ bias,        // [N]
    const float* __restrict__ wscale,
    const float* __restrict__ iscale,
    int M, int N, int K) {
    __shared__ __align__(16) unsigned char As[2 * 32768];
    __shared__ __align__(16) unsigned char Bs[2 * 32768];

    const int tid  = threadIdx.x;
    const int lane = tid & 63;
    const int wv   = tid >> 6;          // 8 waves
    const int wm   = wv >> 2;           // 2 (M) x 4 (N) wave grid
    const int wn   = wv & 3;
    const int r16  = lane & 15;
    const int cq   = lane >> 4;         // 0..3

    const int bm = blockIdx.y * 256;    // linear block order (round-2 measured)
    const int bn = blockIdx.x * 256;

    // staging: 32 x 1 KB units per operand tile; wave wv owns units wv*4+j
    const unsigned char* ga[4];
    const unsigned char* gb[4];
    int lo[4];
#pragma unroll
    for (int j = 0; j < 4; ++j) {
        const int u   = wv * 4 + j;     // 0..31
        const int rb  = u >> 1;
        const int rg  = u & 1;
        const int row = rb * 16 + r16;
        const int col = cq * 32 + rg * 16;   // per-lane pre-swizzled source
        ga[j] = A  + (size_t)(bm + row) * K + col;
        gb[j] = Bt + (size_t)(bn + row) * K + col;
        lo[j] = u * 1024;                    // wave-uniform LDS offset
    }

    floatx16 acc[4][2] = {};            // 4 m-blocks x 2 n-blocks
    const int NT = K >> 7;              // K / 128

    // per-lane fragment base: lane l -> row (l&31), k-bytes (l>>5)*32..
    const int labase = ((lane >> 4) & 1) * 2048 + (lane & 15) * 16 + (lane >> 5) * 256;

    // prologue: stage tile 0 into buffer 0, drain, one barrier
#pragma unroll
    for (int j = 0; j < 4; ++j) {
        gload16(ga[j], &As[lo[j]]);
        gload16(gb[j], &Bs[lo[j]]);
        ga[j] += 128; gb[j] += 128;
    }
    asm volatile("s_waitcnt vmcnt(0)" ::: "memory");
    __builtin_amdgcn_s_barrier();
    __builtin_amdgcn_sched_barrier(0);

    union U8 { intx8 v; uint4 q[2]; };

#define READ_FRAG(dst, p)                                           \
    do {                                                            \
        U8 _u;                                                      \
        _u.q[0] = *(const uint4*)(p);                               \
        _u.q[1] = *(const uint4*)((p) + 1024);                      \
        (dst) = _u.v;                                               \
    } while (0)

#define MFMA4(afA, afB, mA, mB, b0_, b1_)                                   \
    do {                                                                    \
        __builtin_amdgcn_s_setprio(1);                                      \
        acc[mA][0] = __builtin_amdgcn_mfma_scale_f32_32x32x64_f8f6f4(       \
            afA, b0_, acc[mA][0], 0, 0, 0, 0x7F7F7F7F, 0, 0x7F7F7F7F);      \
        acc[mA][1] = __builtin_amdgcn_mfma_scale_f32_32x32x64_f8f6f4(       \
            afA, b1_, acc[mA][1], 0, 0, 0, 0x7F7F7F7F, 0, 0x7F7F7F7F);      \
        acc[mB][0] = __builtin_amdgcn_mfma_scale_f32_32x32x64_f8f6f4(       \
            afB, b0_, acc[mB][0], 0, 0, 0, 0x7F7F7F7F, 0, 0x7F7F7F7F);      \
        acc[mB][1] = __builtin_amdgcn_mfma_scale_f32_32x32x64_f8f6f4(       \
            afB, b1_, acc[mB][1], 0, 0, 0, 0x7F7F7F7F, 0, 0x7F7F7F7F);      \
        __builtin_amdgcn_s_setprio(0);                                      \
    } while (0)

    for (int kt = 0; kt < NT; ++kt) {
        const unsigned char* Ab = &As[(kt & 1) * 32768];
        const unsigned char* Bb = &Bs[(kt & 1) * 32768];
        unsigned char* An = &As[((kt + 1) & 1) * 32768];
        unsigned char* Bn = &Bs[((kt + 1) & 1) * 32768];

        // stage BOTH operands 1-ahead at tile top (WAR-safe behind the
        // boundary barrier; drain at tile end is latency-free)
        if (kt + 1 < NT) {
#pragma unroll
            for (int j = 0; j < 4; ++j) {
                gload16(ga[j], An + lo[j]);
                gload16(gb[j], Bn + lo[j]);
                ga[j] += 128; gb[j] += 128;
            }
        }
        __builtin_amdgcn_sched_barrier(0);   // keep DMA issue at tile top

        const unsigned char* aB = Ab + labase;
        const unsigned char* bB = Bb + labase;
        intx8 b00, b01, b10, b11, af0, af1, ag0, ag1;

        // pipelined reads: 16 ops up front (ks0 + all B), compiler emits
        // counted lgkmcnt before each dependent MFMA quad
        READ_FRAG(b00, bB + (wn * 4 + 0) * 2048);
        READ_FRAG(b01, bB + (wn * 4 + 2) * 2048);
        READ_FRAG(af0, aB + (wm * 8 + 0) * 2048);
        READ_FRAG(af1, aB + (wm * 8 + 2) * 2048);
        READ_FRAG(b10, bB + (wn * 4 + 0) * 2048 + 512);
        READ_FRAG(b11, bB + (wn * 4 + 2) * 2048 + 512);
        READ_FRAG(ag0, aB + (wm * 8 + 4) * 2048);
        READ_FRAG(ag1, aB + (wm * 8 + 6) * 2048);

        MFMA4(af0, af1, 0, 1, b00, b01);                 // P0 (mb0,1 x ks0)

        READ_FRAG(af0, aB + (wm * 8 + 0) * 2048 + 512);  // P2 frags (ks1)
        READ_FRAG(af1, aB + (wm * 8 + 2) * 2048 + 512);

        MFMA4(ag0, ag1, 2, 3, b00, b01);                 // P1 (mb2,3 x ks0)

        READ_FRAG(ag0, aB + (wm * 8 + 4) * 2048 + 512);  // P3 frags (ks1)
        READ_FRAG(ag1, aB + (wm * 8 + 6) * 2048 + 512);

        MFMA4(af0, af1, 0, 1, b10, b11);                 // P2 (mb0,1 x ks1)
        MFMA4(ag0, ag1, 2, 3, b10, b11);                 // P3 (mb2,3 x ks1)

        // boundary: next tile's staging landed long ago; one barrier
        asm volatile("s_waitcnt vmcnt(0)" ::: "memory");
        __builtin_amdgcn_s_barrier();
        __builtin_amdgcn_sched_barrier(0);
    }
    (void)M; (void)r16; (void)cq;
#undef READ_FRAG
#undef MFMA4

    // epilogue: C/D 32x32 layout: col=lane&31, row=(r&3)+8*(r>>2)+4*(lane>>5)
    const float scale = iscale[0] * wscale[0];
    const int colb = bn + wn * 64 + (lane & 31);
    const float bv0 = bias[colb];
    const float bv1 = bias[colb + 32];
    const int rowb = bm + wm * 128 + 4 * (lane >> 5);
#pragma unroll
    for (int mb = 0; mb < 4; ++mb) {
#pragma unroll
        for (int r = 0; r < 16; ++r) {
            const int row = rowb + mb * 32 + (r & 3) + 8 * (r >> 2);
            float* cp = C + (size_t)row * N + colb;
            cp[0]  = acc[mb][0][r] * scale + bv0;   // 128 B across lanes
            cp[32] = acc[mb][1][r] * scale + bv1;   // adjacent 128 B
        }
    }
}

extern "C" void kernel_launch(void* const* d_in, const int* in_sizes, int n_in,
                              void* d_out, int out_size, void* d_ws, size_t ws_size,
                              hipStream_t stream) {
    const float* x          = (const float*)d_in[0];
    const unsigned char* w  = (const unsigned char*)d_in[1];
    const float* wscale     = (const float*)d_in[2];
    const float* iscale     = (const float*)d_in[3];
    const float* bias       = (const float*)d_in[4];
    float* out              = (float*)d_out;

    const int D_OUT = in_sizes[4];            // 8192
    const int D_IN  = in_sizes[1] / D_OUT;    // 2048
    const int M     = in_sizes[0] / D_IN;     // 8192

    int* flag         = (int*)d_ws;
    unsigned char* q  = (unsigned char*)d_ws + 256;
    unsigned char* wt = q + (size_t)M * D_IN;

    detect_kernel<<<1, 256, 0, stream>>>((const unsigned int*)w, flag);
    const int n8 = (M * D_IN) / 8;
    quant_kernel<<<(n8 + 255) / 256, 256, 0, stream>>>(x, (unsigned int*)q, iscale, n8);
    dim3 tg(D_OUT / 64, D_IN / 64);
    ingest_kernel<<<tg, 256, 0, stream>>>(w, wt, flag, D_IN, D_OUT);
    gemm_mxfp8_kernel<<<dim3(D_OUT / 256, M / 256), 512, 0, stream>>>(
        q, wt, out, bias, wscale, iscale, M, D_OUT, D_IN);
}

// Round 9
// 503.535 us; speedup vs baseline: 1.0674x; 1.0674x over previous
//
#include <hip/hip_runtime.h>

typedef __attribute__((ext_vector_type(4)))  float floatx4;
typedef __attribute__((ext_vector_type(16))) float floatx16;
typedef __attribute__((ext_vector_type(8)))  int   intx8;

// ---------------------------------------------------------------------------
// pack 4 floats (already clipped to +-448) into 4 e4m3 bytes, RNE
// ---------------------------------------------------------------------------
__device__ __forceinline__ unsigned int pack4_fp8(float f0, float f1, float f2, float f3) {
    int v = __builtin_amdgcn_cvt_pk_fp8_f32(f0, f1, 0, false);   // bytes 0,1
    v = __builtin_amdgcn_cvt_pk_fp8_f32(f2, f3, v, true);        // bytes 2,3
    return (unsigned int)v;
}

// async global->LDS, 16 B per lane. LDS dest is wave-uniform; HW writes
// dest + lane*16. Global src is per-lane (pre-swizzled to match).
__device__ __forceinline__ void gload16(const unsigned char* g, unsigned char* l) {
    __builtin_amdgcn_global_load_lds(
        (const __attribute__((address_space(1))) unsigned int*)g,
        (__attribute__((address_space(3))) unsigned int*)l, 16, 0, 0);
}

// ---------------------------------------------------------------------------
// ingest body: weight [K,N] tile (any of 3 dtypes) -> Wt [N,K] fp8 bytes,
// via 64x64 LDS tile (verified rounds 0-8).
// ---------------------------------------------------------------------------
template <int MODE>
__device__ __forceinline__ void ingest_body(const unsigned char* __restrict__ W,
                                            unsigned char* __restrict__ Wt,
                                            int K, int N, int k0, int n0,
                                            unsigned char (*tile)[68]) {
    const int t = threadIdx.x;          // 256 threads
    const int kr = t >> 2;              // k-row within tile
    const int cg = (t & 3) * 16;        // n-column group (16 values)
    const size_t eidx = (size_t)(k0 + kr) * N + (n0 + cg);  // element index

    unsigned int w4[4];
    if constexpr (MODE == 0) {          // raw fp8 bytes
        uint4 v = *(const uint4*)(W + eidx);
        w4[0] = v.x; w4[1] = v.y; w4[2] = v.z; w4[3] = v.w;
    } else if constexpr (MODE == 1) {   // bf16-upcast (2 B/elem)
        const uint4* p = (const uint4*)((const unsigned short*)W + eidx);
        uint4 A0 = p[0], A1 = p[1];
        unsigned int uw[8] = {A0.x, A0.y, A0.z, A0.w, A1.x, A1.y, A1.z, A1.w};
#pragma unroll
        for (int g = 0; g < 4; ++g) {
            float f0 = __uint_as_float((uw[2 * g] & 0xFFFFu) << 16);
            float f1 = __uint_as_float((uw[2 * g] >> 16) << 16);
            float f2 = __uint_as_float((uw[2 * g + 1] & 0xFFFFu) << 16);
            float f3 = __uint_as_float((uw[2 * g + 1] >> 16) << 16);
            w4[g] = pack4_fp8(f0, f1, f2, f3);
        }
    } else {                            // f32-upcast (4 B/elem)
        const float4* p = (const float4*)((const float*)W + eidx);
#pragma unroll
        for (int g = 0; g < 4; ++g) {
            float4 f = p[g];
            w4[g] = pack4_fp8(f.x, f.y, f.z, f.w);
        }
    }
#pragma unroll
    for (int g = 0; g < 4; ++g)
        *(unsigned int*)&tile[kr][cg + 4 * g] = w4[g];   // 4B-aligned (68%4==0)
    __syncthreads();

    const int nr = t >> 2;
    const int kg = (t & 3) * 16;
    uint4 o;
    unsigned int w[4];
#pragma unroll
    for (int g = 0; g < 4; ++g) {
        unsigned int b0 = tile[kg + g * 4 + 0][nr];
        unsigned int b1 = tile[kg + g * 4 + 1][nr];
        unsigned int b2 = tile[kg + g * 4 + 2][nr];
        unsigned int b3 = tile[kg + g * 4 + 3][nr];
        w[g] = b0 | (b1 << 8) | (b2 << 16) | (b3 << 24);
    }
    o.x = w[0]; o.y = w[1]; o.z = w[2]; o.w = w[3];
    *(uint4*)(Wt + (size_t)(n0 + nr) * K + k0 + kg) = o;  // 16B-aligned
}

// ---------------------------------------------------------------------------
// Kernel 1 (merged prep): blocks [0,nbq) quantize x -> q fp8; blocks
// [nbq, ...) ingest W -> Wt with PER-BLOCK dtype detect (uniform result).
// Merging removes 2 launch boundaries and overlaps quant with ingest
// (probe of the constant ~310us non-gemm pool).
// ---------------------------------------------------------------------------
__global__ __launch_bounds__(256) void prep_kernel(
    const float* __restrict__ x, unsigned int* __restrict__ q,
    const float* __restrict__ iscale, int n8, int nbq,
    const unsigned char* __restrict__ W, unsigned char* __restrict__ Wt,
    int K, int N) {
    __shared__ int ok[2];
    __shared__ __align__(16) unsigned char tile[64][68];

    if ((int)blockIdx.x < nbq) {        // ---- quant part (block-uniform)
        int i = blockIdx.x * 256 + threadIdx.x;
        if (i >= n8) return;
        float s = iscale[0];
        const float4* xv = (const float4*)x;
        float4 a = xv[2 * i];
        float4 b = xv[2 * i + 1];
        float v[8] = {a.x, a.y, a.z, a.w, b.x, b.y, b.z, b.w};
#pragma unroll
        for (int j = 0; j < 8; ++j) {
            float t = v[j] / s;
            v[j] = fminf(fmaxf(t, -448.0f), 448.0f);
        }
        q[2 * i]     = pack4_fp8(v[0], v[1], v[2], v[3]);
        q[2 * i + 1] = pack4_fp8(v[4], v[5], v[6], v[7]);
        return;
    }

    // ---- ingest part: folded dtype detect over first 16KB (L2-hot)
    if (threadIdx.x == 0) { ok[0] = 1; ok[1] = 1; }
    __syncthreads();
    int f32ok = 1, bf16ok = 1;
#pragma unroll
    for (int i = 0; i < 16; ++i) {
        unsigned int w = ((const unsigned int*)W)[threadIdx.x * 16 + i];
        if (w & 0x000FFFFFu) f32ok = 0;
        if (w & 0x000F000Fu) bf16ok = 0;
    }
    if (!f32ok)  atomicAnd(&ok[0], 0);
    if (!bf16ok) atomicAnd(&ok[1], 0);
    __syncthreads();
    const int mode = ok[0] ? 2 : (ok[1] ? 1 : 0);   // block-uniform

    const int bx = blockIdx.x - nbq;
    const int ntn = N >> 6;
    const int n0 = (bx % ntn) * 64;
    const int k0 = (bx / ntn) * 64;
    if (mode == 0)      ingest_body<0>(W, Wt, K, N, k0, n0, tile);
    else if (mode == 1) ingest_body<1>(W, Wt, K, N, k0, n0, tile);
    else                ingest_body<2>(W, Wt, K, N, k0, n0, tile);
}

// ---------------------------------------------------------------------------
// Kernel 2: MX-scaled fp8 GEMM (scales = 1.0), 256x256 tile, BK=64,
// 8 waves (2M x 4N), 32x32x64 MFMA, 2 phases/tile, counted vmcnt.
//
// ROUND-9 CHANGE (occupancy x structure): r7's schedule at 1 block/CU pins
// MfmaUtil at 30% = exactly MFMA-pipe/wall (68.7 cyc/instr calibrated from
// the 4686 TF ubench); the other 70% is LDS-port time and waits that ONE
// block's 2 waves/SIMD cannot overlap. BK 128->64 halves LDS to 64 KB ->
// 2 blocks/CU; de-synced blocks interleave port-storms with MFMA phases
// (m114 implicit overlap) on top of the proven r7 phase structure.
//
// LDS layout (per 16 KB operand tile): 16 units of 1 KB; unit u holds rows
// u*16+(l&15), k-bytes (l>>4)*16..+15 at byte u*1024 + l*16 (DMA-linear).
// Fragment (32x32x64, mb): lane l needs row mb*32+(l&31), kb (l>>5)*32+0..31
//   = two b128 at (mb*2 + ((l>>4)&1))*1024 + ((l&15) + (l>>5)*32)*16 (+256).
// Wave footprint per frag-read: 4 dense 256B chunks -> conflict-free.
//
// Rolling DMA (per wave, 2 units/operand): P0: A(t+1); P1: B(t+2) (B(t)
// reads confined to P0, so Bs[t&1] rewrite is barrier-separated); boundary
// vmcnt(2) keeps only B(t+2) in flight (FIFO-walked; tails drain to 0).
// Prologue: A(0)+B(0)+B(1), wait vmcnt(2).
// ---------------------------------------------------------------------------
__global__ __launch_bounds__(512, 2) void gemm_mxfp8_kernel(
    const unsigned char* __restrict__ A,   // [M,K] fp8
    const unsigned char* __restrict__ Bt,  // [N,K] fp8
    float* __restrict__ C,                 // [M,N] fp32
    const float* __restrict__ bias,        // [N]
    const float* __restrict__ wscale,
    const float* __restrict__ iscale,
    int M, int N, int K) {
    __shared__ __align__(16) unsigned char As[2 * 16384];
    __shared__ __align__(16) unsigned char Bs[2 * 16384];

    const int tid  = threadIdx.x;
    const int lane = tid & 63;
    const int wv   = tid >> 6;          // 8 waves
    const int wm   = wv >> 2;           // 2 (M) x 4 (N) wave grid
    const int wn   = wv & 3;
    const int r16  = lane & 15;
    const int cq   = lane >> 4;         // 0..3

    const int bm = blockIdx.y * 256;
    const int bn = blockIdx.x * 256;

    // staging: 16 x 1 KB units per operand tile; wave wv owns units wv*2+j
    const unsigned char* ga[2];
    const unsigned char* gb[2];
    int lo[2];
#pragma unroll
    for (int j = 0; j < 2; ++j) {
        const int u   = wv * 2 + j;          // 0..15
        const int row = u * 16 + r16;
        const int col = cq * 16;             // covers K 0..63
        ga[j] = A  + (size_t)(bm + row) * K + col;
        gb[j] = Bt + (size_t)(bn + row) * K + col;
        lo[j] = u * 1024;
    }

    floatx16 acc[4][2] = {};            // 4 m-blocks x 2 n-blocks
    const int NT = K >> 6;              // K / 64

    // per-lane fragment base (derivation in header)
    const int labase = ((lane >> 4) & 1) * 1024 + (lane & 15) * 16 + (lane >> 5) * 512;

    // prologue: A(0)+B(0) -> buf0, B(1) -> buf1, keep newest 2 in flight
#pragma unroll
    for (int j = 0; j < 2; ++j) {
        gload16(ga[j], &As[lo[j]]);
        gload16(gb[j], &Bs[lo[j]]);
        ga[j] += 64; gb[j] += 64;
    }
    if (NT > 1) {
#pragma unroll
        for (int j = 0; j < 2; ++j) {
            gload16(gb[j], &Bs[16384 + lo[j]]);   // B(1) -> buf1
            gb[j] += 64;                          // gb -> tile 2
        }
        asm volatile("s_waitcnt vmcnt(2)" ::: "memory");
    } else {
        asm volatile("s_waitcnt vmcnt(0)" ::: "memory");
    }
    __builtin_amdgcn_s_barrier();
    __builtin_amdgcn_sched_barrier(0);

    union U8 { intx8 v; uint4 q[2]; };

#define READ_FRAG(dst, p)                                           \
    do {                                                            \
        U8 _u;                                                      \
        _u.q[0] = *(const uint4*)(p);                               \
        _u.q[1] = *(const uint4*)((p) + 256);                       \
        (dst) = _u.v;                                               \
    } while (0)

#define MFMA4(afA, afB, mA, mB, b0_, b1_)                                   \
    do {                                                                    \
        __builtin_amdgcn_s_setprio(1);                                      \
        acc[mA][0] = __builtin_amdgcn_mfma_scale_f32_32x32x64_f8f6f4(       \
            afA, b0_, acc[mA][0], 0, 0, 0, 0x7F7F7F7F, 0, 0x7F7F7F7F);      \
        acc[mA][1] = __builtin_amdgcn_mfma_scale_f32_32x32x64_f8f6f4(       \
            afA, b1_, acc[mA][1], 0, 0, 0, 0x7F7F7F7F, 0, 0x7F7F7F7F);      \
        acc[mB][0] = __builtin_amdgcn_mfma_scale_f32_32x32x64_f8f6f4(       \
            afB, b0_, acc[mB][0], 0, 0, 0, 0x7F7F7F7F, 0, 0x7F7F7F7F);      \
        acc[mB][1] = __builtin_amdgcn_mfma_scale_f32_32x32x64_f8f6f4(       \
            afB, b1_, acc[mB][1], 0, 0, 0, 0x7F7F7F7F, 0, 0x7F7F7F7F);      \
        __builtin_amdgcn_s_setprio(0);                                      \
    } while (0)

#define PHASE_WAIT()                                             \
    do {                                                         \
        __builtin_amdgcn_s_barrier();                            \
        asm volatile("s_waitcnt lgkmcnt(0)" ::: "memory");       \
        __builtin_amdgcn_sched_barrier(0);                       \
    } while (0)

    for (int kt = 0; kt < NT; ++kt) {
        const unsigned char* Ab = &As[(kt & 1) * 16384];
        const unsigned char* Bb = &Bs[(kt & 1) * 16384];
        unsigned char* An  = &As[((kt + 1) & 1) * 16384];  // A(t+1) target
        unsigned char* Bn2 = &Bs[(kt & 1) * 16384];        // B(t+2) target
        const bool pfA = (kt + 1 < NT);
        const bool pfB = (kt + 2 < NT);

        const unsigned char* aB = Ab + labase;
        const unsigned char* bB = Bb + labase;
        intx8 b0, b1, a0, a1;

        // ---- P0: B nb0,nb1 + A mb0,mb1 (8 b128); DMA A(t+1)
        READ_FRAG(b0, bB + (wn * 2 + 0) * 2048);
        READ_FRAG(b1, bB + (wn * 2 + 1) * 2048);
        READ_FRAG(a0, aB + (wm * 4 + 0) * 2048);
        READ_FRAG(a1, aB + (wm * 4 + 1) * 2048);
        if (pfA) {
            gload16(ga[0], An + lo[0]); gload16(ga[1], An + lo[1]);
            ga[0] += 64; ga[1] += 64;
        }
        PHASE_WAIT();
        MFMA4(a0, a1, 0, 1, b0, b1);
        __builtin_amdgcn_s_barrier();

        // ---- P1: A mb2,mb3 (4 b128); DMA B(t+2) (B(t) reads done @P0)
        READ_FRAG(a0, aB + (wm * 4 + 2) * 2048);
        READ_FRAG(a1, aB + (wm * 4 + 3) * 2048);
        if (pfB) {
            gload16(gb[0], Bn2 + lo[0]); gload16(gb[1], Bn2 + lo[1]);
            gb[0] += 64; gb[1] += 64;
        }
        PHASE_WAIT();
        MFMA4(a0, a1, 2, 3, b0, b1);
        if (pfB) {      // steady state: keep newest 2 (B(t+2)) in flight
            asm volatile("s_waitcnt vmcnt(2)" ::: "memory");
        } else {
            asm volatile("s_waitcnt vmcnt(0)" ::: "memory");
        }
        __builtin_amdgcn_s_barrier();
        __builtin_amdgcn_sched_barrier(0);
    }
    (void)M;
#undef READ_FRAG
#undef MFMA4
#undef PHASE_WAIT

    // epilogue: C/D 32x32 layout: col=lane&31, row=(r&3)+8*(r>>2)+4*(lane>>5)
    const float scale = iscale[0] * wscale[0];
    const int colb = bn + wn * 64 + (lane & 31);
    const float bv0 = bias[colb];
    const float bv1 = bias[colb + 32];
    const int rowb = bm + wm * 128 + 4 * (lane >> 5);
#pragma unroll
    for (int mb = 0; mb < 4; ++mb) {
#pragma unroll
        for (int r = 0; r < 16; ++r) {
            const int row = rowb + mb * 32 + (r & 3) + 8 * (r >> 2);
            float* cp = C + (size_t)row * N + colb;
            cp[0]  = acc[mb][0][r] * scale + bv0;   // 128 B across lanes
            cp[32] = acc[mb][1][r] * scale + bv1;   // adjacent 128 B
        }
    }
}

extern "C" void kernel_launch(void* const* d_in, const int* in_sizes, int n_in,
                              void* d_out, int out_size, void* d_ws, size_t ws_size,
                              hipStream_t stream) {
    const float* x          = (const float*)d_in[0];
    const unsigned char* w  = (const unsigned char*)d_in[1];
    const float* wscale     = (const float*)d_in[2];
    const float* iscale     = (const float*)d_in[3];
    const float* bias       = (const float*)d_in[4];
    float* out              = (float*)d_out;

    const int D_OUT = in_sizes[4];            // 8192
    const int D_IN  = in_sizes[1] / D_OUT;    // 2048
    const int M     = in_sizes[0] / D_IN;     // 8192

    unsigned char* q  = (unsigned char*)d_ws + 256;
    unsigned char* wt = q + (size_t)M * D_IN;

    const int n8  = (M * D_IN) / 8;
    const int nbq = (n8 + 255) / 256;
    const int nbi = (D_IN / 64) * (D_OUT / 64);
    prep_kernel<<<nbq + nbi, 256, 0, stream>>>(
        x, (unsigned int*)q, iscale, n8, nbq, w, wt, D_IN, D_OUT);
    gemm_mxfp8_kernel<<<dim3(D_OUT / 256, M / 256), 512, 0, stream>>>(
        q, wt, out, bias, wscale, iscale, M, D_OUT, D_IN);
}